// Round 3
// baseline (292.242 us; speedup 1.0000x reference)
//
#include <hip/hip_runtime.h>

#define N_D 32
constexpr float EPS = 1e-12f;

// ---- bf16 helpers (manual, round-to-nearest-even) ----
__device__ __forceinline__ ushort f2b(float f) {
    unsigned u = __float_as_uint(f);
    return (ushort)((u + 0x7fffu + ((u >> 16) & 1u)) >> 16);
}
__device__ __forceinline__ float b2f(ushort h) {
    return __uint_as_float(((unsigned)h) << 16);
}

// ---------------------------------------------------------------------------
// K1: per-node norm + bf16 normalized pack. 8 lanes/node, float4 in, ushort4 out.
// ---------------------------------------------------------------------------
__global__ void agnn_norm_pack(const float* __restrict__ x,
                               ushort* __restrict__ xnh,
                               float* __restrict__ normv,
                               int n_nodes) {
    int gid  = blockIdx.x * blockDim.x + threadIdx.x;
    int node = gid >> 3;
    int lane = gid & 7;
    if (node >= n_nodes) return;

    float4 v = reinterpret_cast<const float4*>(x + (size_t)node * N_D)[lane];
    float ss = v.x * v.x + v.y * v.y + v.z * v.z + v.w * v.w;
    ss += __shfl_xor(ss, 1, 8);
    ss += __shfl_xor(ss, 2, 8);
    ss += __shfl_xor(ss, 4, 8);

    float norm = sqrtf(ss);
    float r = 1.0f / fmaxf(norm, EPS);
    ushort4 h;
    h.x = f2b(v.x * r); h.y = f2b(v.y * r);
    h.z = f2b(v.z * r); h.w = f2b(v.w * r);
    reinterpret_cast<ushort4*>(xnh + (size_t)node * N_D)[lane] = h;
    if (lane == 0) normv[node] = norm;
}

// ---------------------------------------------------------------------------
// K2: histogram of destination degrees. counts[] pre-zeroed.
// ---------------------------------------------------------------------------
__global__ void agnn_hist_kernel(const int* __restrict__ dst_idx,
                                 int* __restrict__ counts,
                                 int n_edges) {
    int e = blockIdx.x * blockDim.x + threadIdx.x;
    if (e >= n_edges) return;
    atomicAdd(&counts[dst_idx[e]], 1);
}

// ---------------------------------------------------------------------------
// K3a/b/c: exclusive scan counts -> ptr (hierarchical, 3 kernels).
// ---------------------------------------------------------------------------
__global__ void scan_k1(const int* __restrict__ counts,
                        int* __restrict__ ptr,
                        int* __restrict__ bsums,
                        int n) {
    __shared__ int tmp[256];
    int t = threadIdx.x;
    int i = blockIdx.x * 256 + t;
    int v = (i < n) ? counts[i] : 0;
    tmp[t] = v;
    __syncthreads();
    for (int off = 1; off < 256; off <<= 1) {
        int add = (t >= off) ? tmp[t - off] : 0;
        __syncthreads();
        tmp[t] += add;
        __syncthreads();
    }
    if (i < n) ptr[i] = tmp[t] - v;          // exclusive
    if (t == 255) bsums[blockIdx.x] = tmp[255];
}

__global__ void scan_k2(int* __restrict__ bsums, int nb) {
    __shared__ int tmp[512];
    int t = threadIdx.x;
    int v = (t < nb) ? bsums[t] : 0;
    tmp[t] = v;
    __syncthreads();
    for (int off = 1; off < 512; off <<= 1) {
        int add = (t >= off) ? tmp[t - off] : 0;
        __syncthreads();
        tmp[t] += add;
        __syncthreads();
    }
    if (t < nb) bsums[t] = tmp[t] - v;       // exclusive over block sums
}

__global__ void scan_k3(int* __restrict__ ptr,
                        const int* __restrict__ bsums,
                        int n, int total) {
    int i = blockIdx.x * 256 + threadIdx.x;
    if (i < n) ptr[i] += bsums[blockIdx.x];
    if (i == 0) ptr[n] = total;              // sentinel ptr[N] = E
}

// ---------------------------------------------------------------------------
// K4: counting-sort scatter of src indices into CSR buckets. No feature reads
// -> no competing gather stream -> L2 absorbs the 4B scattered writes.
// counts drains back to 0 (re-zeroed by memset each launch).
// ---------------------------------------------------------------------------
__global__ void agnn_permute(const int* __restrict__ src_idx,
                             const int* __restrict__ dst_idx,
                             const int* __restrict__ ptr,
                             int* __restrict__ counts,
                             int* __restrict__ perm_src,
                             int n_edges) {
    int e = blockIdx.x * blockDim.x + threadIdx.x;
    if (e >= n_edges) return;
    int d = dst_idx[e];
    int pos = ptr[d] + atomicSub(&counts[d], 1) - 1;
    perm_src[pos] = src_idx[e];
}

// ---------------------------------------------------------------------------
// K5: fused single-pass softmax + aggregate. One 8-lane group per dst node.
// out_i = (sum_j a_j * norm_j * xn_j) / (sum_j a_j)  -- denominator is
// bucket-uniform so numerator and denominator accumulate in one pass.
// Per edge: ONE 64B bf16 row gather + broadcast loads of perm_src/normv.
// ---------------------------------------------------------------------------
__global__ void agnn_aggr(const ushort* __restrict__ xnh,
                          const float* __restrict__ normv,
                          const int* __restrict__ ptr,
                          const int* __restrict__ perm_src,
                          const float* __restrict__ beta,
                          float* __restrict__ out,
                          int n_nodes) {
    int gid  = blockIdx.x * blockDim.x + threadIdx.x;
    int node = gid >> 3;
    int lane = gid & 7;
    if (node >= n_nodes) return;

    float b = beta[0];

    // dst row (sequential load, lives in registers for the whole bucket)
    ushort4 hd = reinterpret_cast<const ushort4*>(xnh + (size_t)node * N_D)[lane];
    float dx = b2f(hd.x), dy = b2f(hd.y), dz = b2f(hd.z), dw = b2f(hd.w);

    int start = ptr[node];
    int end   = ptr[node + 1];

    float denom = 0.0f;
    float4 acc = make_float4(0.f, 0.f, 0.f, 0.f);

    for (int i = start; i < end; ++i) {
        int s = perm_src[i];                               // group-broadcast
        ushort4 hs = reinterpret_cast<const ushort4*>(
            xnh + (size_t)s * N_D)[lane];                  // the one gather
        float sx = b2f(hs.x), sy = b2f(hs.y), sz = b2f(hs.z), sw = b2f(hs.w);

        float pd = dx * sx + dy * sy + dz * sz + dw * sw;
        pd += __shfl_xor(pd, 1, 8);
        pd += __shfl_xor(pd, 2, 8);
        pd += __shfl_xor(pd, 4, 8);

        float a = __expf(b * pd);       // |b*pd| < 1: no max-shift needed
        float w = a * normv[s];         // fold ||x_src|| back in
        denom += a;
        acc.x += w * sx; acc.y += w * sy; acc.z += w * sz; acc.w += w * sw;
    }

    float inv = (end > start) ? 1.0f / denom : 0.0f;
    float4 o;
    o.x = acc.x * inv; o.y = acc.y * inv; o.z = acc.z * inv; o.w = acc.w * inv;
    reinterpret_cast<float4*>(out + (size_t)node * N_D)[lane] = o;
}

extern "C" void kernel_launch(void* const* d_in, const int* in_sizes, int n_in,
                              void* d_out, int out_size, void* d_ws, size_t ws_size,
                              hipStream_t stream) {
    const float* x    = (const float*)d_in[0];
    const float* beta = (const float*)d_in[1];
    const int*   ei   = (const int*)d_in[2];

    int n_nodes = in_sizes[0] / N_D;
    int n_edges = in_sizes[2] / 2;
    const int* src_idx = ei;
    const int* dst_idx = ei + n_edges;

    float* out = (float*)d_out;

    // ws layout: xnh[N*32 bf16] | perm_src[E int] | normv[N f32] |
    //            ptr[N+1] | counts[N] | bsums[512]   (~15.6 MB)
    char* w = (char*)d_ws;
    ushort* xnh     = (ushort*)w;  w += (size_t)n_nodes * N_D * sizeof(ushort);
    int*   perm_src = (int*)w;     w += (size_t)n_edges * sizeof(int);
    float* normv    = (float*)w;   w += (size_t)n_nodes * sizeof(float);
    int*   ptr      = (int*)w;     w += (size_t)(n_nodes + 1) * sizeof(int);
    int*   counts   = (int*)w;     w += (size_t)n_nodes * sizeof(int);
    int*   bsums    = (int*)w;

    hipMemsetAsync(counts, 0, (size_t)n_nodes * sizeof(int), stream);

    const int tpb = 256;
    int node_blocks = (int)(((long long)n_nodes * 8 + tpb - 1) / tpb);
    int edge_blocks = (n_edges + tpb - 1) / tpb;
    int scan_blocks = (n_nodes + 255) / 256;     // 391 for N=100k (<=512)

    agnn_norm_pack<<<node_blocks, tpb, 0, stream>>>(x, xnh, normv, n_nodes);

    agnn_hist_kernel<<<edge_blocks, tpb, 0, stream>>>(dst_idx, counts, n_edges);

    scan_k1<<<scan_blocks, 256, 0, stream>>>(counts, ptr, bsums, n_nodes);
    scan_k2<<<1, 512, 0, stream>>>(bsums, scan_blocks);
    scan_k3<<<scan_blocks, 256, 0, stream>>>(ptr, bsums, n_nodes, n_edges);

    agnn_permute<<<edge_blocks, tpb, 0, stream>>>(
        src_idx, dst_idx, ptr, counts, perm_src, n_edges);

    agnn_aggr<<<node_blocks, tpb, 0, stream>>>(
        xnh, normv, ptr, perm_src, beta, out, n_nodes);
}

// Round 4
// 252.508 us; speedup vs baseline: 1.1574x; 1.1574x over previous
//
#include <hip/hip_runtime.h>

#define N_D 32
constexpr float EPS = 1e-12f;

// ---- bf16 helpers (manual, round-to-nearest-even) ----
__device__ __forceinline__ ushort f2b(float f) {
    unsigned u = __float_as_uint(f);
    return (ushort)((u + 0x7fffu + ((u >> 16) & 1u)) >> 16);
}
__device__ __forceinline__ float b2f(ushort h) {
    return __uint_as_float(((unsigned)h) << 16);
}

// ---------------------------------------------------------------------------
// K1: per-node norm + bf16 normalized pack. 8 lanes/node.
// ---------------------------------------------------------------------------
__global__ void agnn_norm_pack(const float* __restrict__ x,
                               ushort* __restrict__ xnh,
                               float* __restrict__ normv,
                               int n_nodes) {
    int gid  = blockIdx.x * blockDim.x + threadIdx.x;
    int node = gid >> 3;
    int lane = gid & 7;
    if (node >= n_nodes) return;

    float4 v = reinterpret_cast<const float4*>(x + (size_t)node * N_D)[lane];
    float ss = v.x * v.x + v.y * v.y + v.z * v.z + v.w * v.w;
    ss += __shfl_xor(ss, 1, 8);
    ss += __shfl_xor(ss, 2, 8);
    ss += __shfl_xor(ss, 4, 8);

    float norm = sqrtf(ss);
    float r = 1.0f / fmaxf(norm, EPS);
    ushort4 h;
    h.x = f2b(v.x * r); h.y = f2b(v.y * r);
    h.z = f2b(v.z * r); h.w = f2b(v.w * r);
    reinterpret_cast<ushort4*>(xnh + (size_t)node * N_D)[lane] = h;
    if (lane == 0) normv[node] = norm;
}

// ---------------------------------------------------------------------------
// K2: histogram of destination degrees. counts[] pre-zeroed.
// ---------------------------------------------------------------------------
__global__ void agnn_hist_kernel(const int* __restrict__ dst_idx,
                                 int* __restrict__ counts,
                                 int n_edges) {
    int e = blockIdx.x * blockDim.x + threadIdx.x;
    if (e >= n_edges) return;
    atomicAdd(&counts[dst_idx[e]], 1);
}

// ---------------------------------------------------------------------------
// K3a/b/c: exclusive scan counts -> ptr (hierarchical, 3 kernels).
// ---------------------------------------------------------------------------
__global__ void scan_k1(const int* __restrict__ counts,
                        int* __restrict__ ptr,
                        int* __restrict__ bsums,
                        int n) {
    __shared__ int tmp[256];
    int t = threadIdx.x;
    int i = blockIdx.x * 256 + t;
    int v = (i < n) ? counts[i] : 0;
    tmp[t] = v;
    __syncthreads();
    for (int off = 1; off < 256; off <<= 1) {
        int add = (t >= off) ? tmp[t - off] : 0;
        __syncthreads();
        tmp[t] += add;
        __syncthreads();
    }
    if (i < n) ptr[i] = tmp[t] - v;          // exclusive
    if (t == 255) bsums[blockIdx.x] = tmp[255];
}

__global__ void scan_k2(int* __restrict__ bsums, int nb) {
    __shared__ int tmp[512];
    int t = threadIdx.x;
    int v = (t < nb) ? bsums[t] : 0;
    tmp[t] = v;
    __syncthreads();
    for (int off = 1; off < 512; off <<= 1) {
        int add = (t >= off) ? tmp[t - off] : 0;
        __syncthreads();
        tmp[t] += add;
        __syncthreads();
    }
    if (t < nb) bsums[t] = tmp[t] - v;       // exclusive over block sums
}

__global__ void scan_k3(int* __restrict__ ptr,
                        const int* __restrict__ bsums,
                        int n, int total) {
    int i = blockIdx.x * 256 + threadIdx.x;
    if (i < n) ptr[i] += bsums[blockIdx.x];
    if (i == 0) ptr[n] = total;              // sentinel ptr[N] = E
}

// ---------------------------------------------------------------------------
// K4: XCD-sliced counting-sort scatter.
// dst-space is cut into 8 contiguous slices; perm_src positions for slice s
// form a contiguous range, so each cache line of perm_src belongs to one
// slice. Blocks with blockIdx&7==s (round-robin XCD mapping) form subgrid s
// and grid-stride over ALL edges, writing only slice-s edges. Result: each
// perm_src line is written from a single XCD -> L2 write-combines the 16
// 4B entries -> writeback ~= buffer size instead of 64B per edge.
// Re-scanned dst reads are served by the shared 256MB L3.
// ---------------------------------------------------------------------------
__global__ void agnn_permute_sliced(const int* __restrict__ src_idx,
                                    const int* __restrict__ dst_idx,
                                    const int* __restrict__ ptr,
                                    int* __restrict__ counts,
                                    int* __restrict__ perm_src,
                                    int n_edges, int slice_div) {
    int slice  = blockIdx.x & 7;
    int sub    = blockIdx.x >> 3;
    int nsub   = gridDim.x >> 3;
    int stride = nsub * blockDim.x;
    for (int e = sub * blockDim.x + threadIdx.x; e < n_edges; e += stride) {
        int d = dst_idx[e];
        if (d / slice_div == slice) {
            int pos = ptr[d] + atomicSub(&counts[d], 1) - 1;
            perm_src[pos] = src_idx[e];
        }
    }
}

// ---------------------------------------------------------------------------
// K5: fused single-pass softmax + aggregate. One 8-lane group per dst node.
// out_i = (sum_j a_j * norm_j * xn_j) / (sum_j a_j); denominator is
// bucket-uniform so both accumulate in one pass. One 64B gather per edge.
// ---------------------------------------------------------------------------
__global__ void agnn_aggr(const ushort* __restrict__ xnh,
                          const float* __restrict__ normv,
                          const int* __restrict__ ptr,
                          const int* __restrict__ perm_src,
                          const float* __restrict__ beta,
                          float* __restrict__ out,
                          int n_nodes) {
    int gid  = blockIdx.x * blockDim.x + threadIdx.x;
    int node = gid >> 3;
    int lane = gid & 7;
    if (node >= n_nodes) return;

    float b = beta[0];

    ushort4 hd = reinterpret_cast<const ushort4*>(xnh + (size_t)node * N_D)[lane];
    float dx = b2f(hd.x), dy = b2f(hd.y), dz = b2f(hd.z), dw = b2f(hd.w);

    int start = ptr[node];
    int end   = ptr[node + 1];

    float denom = 0.0f;
    float4 acc = make_float4(0.f, 0.f, 0.f, 0.f);

    for (int i = start; i < end; ++i) {
        int s = perm_src[i];                               // group-broadcast
        ushort4 hs = reinterpret_cast<const ushort4*>(
            xnh + (size_t)s * N_D)[lane];                  // the one gather
        float sx = b2f(hs.x), sy = b2f(hs.y), sz = b2f(hs.z), sw = b2f(hs.w);

        float pd = dx * sx + dy * sy + dz * sz + dw * sw;
        pd += __shfl_xor(pd, 1, 8);
        pd += __shfl_xor(pd, 2, 8);
        pd += __shfl_xor(pd, 4, 8);

        float a = __expf(b * pd);       // |b*pd| < 1: no max-shift needed
        float w = a * normv[s];         // fold ||x_src|| back in
        denom += a;
        acc.x += w * sx; acc.y += w * sy; acc.z += w * sz; acc.w += w * sw;
    }

    float inv = (end > start) ? 1.0f / denom : 0.0f;
    float4 o;
    o.x = acc.x * inv; o.y = acc.y * inv; o.z = acc.z * inv; o.w = acc.w * inv;
    reinterpret_cast<float4*>(out + (size_t)node * N_D)[lane] = o;
}

extern "C" void kernel_launch(void* const* d_in, const int* in_sizes, int n_in,
                              void* d_out, int out_size, void* d_ws, size_t ws_size,
                              hipStream_t stream) {
    const float* x    = (const float*)d_in[0];
    const float* beta = (const float*)d_in[1];
    const int*   ei   = (const int*)d_in[2];

    int n_nodes = in_sizes[0] / N_D;
    int n_edges = in_sizes[2] / 2;
    const int* src_idx = ei;
    const int* dst_idx = ei + n_edges;

    float* out = (float*)d_out;

    // ws layout: xnh[N*32 bf16] | perm_src[E int] | normv[N f32] |
    //            ptr[N+1] | counts[N] | bsums[512]   (~15.6 MB)
    char* w = (char*)d_ws;
    ushort* xnh     = (ushort*)w;  w += (size_t)n_nodes * N_D * sizeof(ushort);
    int*   perm_src = (int*)w;     w += (size_t)n_edges * sizeof(int);
    float* normv    = (float*)w;   w += (size_t)n_nodes * sizeof(float);
    int*   ptr      = (int*)w;     w += (size_t)(n_nodes + 1) * sizeof(int);
    int*   counts   = (int*)w;     w += (size_t)n_nodes * sizeof(int);
    int*   bsums    = (int*)w;

    hipMemsetAsync(counts, 0, (size_t)n_nodes * sizeof(int), stream);

    const int tpb = 256;
    int node_blocks = (int)(((long long)n_nodes * 8 + tpb - 1) / tpb);
    int edge_blocks = (n_edges + tpb - 1) / tpb;
    int scan_blocks = (n_nodes + 255) / 256;     // 391 for N=100k (<=512)
    int slice_div   = (n_nodes + 7) / 8;         // contiguous dst slices

    agnn_norm_pack<<<node_blocks, tpb, 0, stream>>>(x, xnh, normv, n_nodes);

    agnn_hist_kernel<<<edge_blocks, tpb, 0, stream>>>(dst_idx, counts, n_edges);

    scan_k1<<<scan_blocks, 256, 0, stream>>>(counts, ptr, bsums, n_nodes);
    scan_k2<<<1, 512, 0, stream>>>(bsums, scan_blocks);
    scan_k3<<<scan_blocks, 256, 0, stream>>>(ptr, bsums, n_nodes, n_edges);

    // 2048 blocks = 8 subgrids x 256; 8 blocks/CU, full occupancy
    agnn_permute_sliced<<<2048, tpb, 0, stream>>>(
        src_idx, dst_idx, ptr, counts, perm_src, n_edges, slice_div);

    agnn_aggr<<<node_blocks, tpb, 0, stream>>>(
        xnh, normv, ptr, perm_src, beta, out, n_nodes);
}